// Round 5
// baseline (172.966 us; speedup 1.0000x reference)
//
#include <hip/hip_runtime.h>
#include <hip/hip_bf16.h>

#define M_DIM 4096
#define N_DIM 16384
#define K_DIM 256

typedef short short8 __attribute__((ext_vector_type(8)));
typedef float f32x4 __attribute__((ext_vector_type(4)));
typedef unsigned int u32x2 __attribute__((ext_vector_type(2)));

// fp32 -> bf16 (RNE) pack of two floats into one u32 (lo = first elem)
__device__ __forceinline__ unsigned int pk2bf(float lo, float hi) {
    unsigned int a = __float_as_uint(lo);
    unsigned int b = __float_as_uint(hi);
    a = (a + 0x7FFFu + ((a >> 16) & 1u)) >> 16;
    b = (b + 0x7FFFu + ((b >> 16) & 1u)) & 0xFFFF0000u;
    return a | b;
}

// ---------------------------------------------------------------------------
// Fully fused: out[M][N] = x[M][K] @ (mask ⊙ W)[K][N] + bias, fp32.
// Mask + f32->bf16 conversion folded into the LDS staging (no pre-pass, no ws).
// 128x128 tile, BK=32 double-buffered (32 KB LDS) -> 3 blocks/CU for store
// drain coverage (kernel is HBM-write-bound: 256 MB out = 41 us floor).
// 4 waves (2x2), 4x4 frags of mfma_f32_16x16x32_bf16, swapped operands
// (D[n][m], verified R2): lane holds 4 consecutive n -> f32x4 stores.
// ---------------------------------------------------------------------------
constexpr int BM = 128, BN = 128, BK = 32;
constexpr int NKT = K_DIM / BK;   // 8 K-steps

__global__ __launch_bounds__(256, 3) void fused_gemm_kernel(
        const float* __restrict__ X,      // [M][K] f32
        const float* __restrict__ W,      // [K][N] f32 (natural layout)
        const float* __restrict__ bias,   // [N] f32
        float* __restrict__ out) {        // [M][N] f32
    __shared__ unsigned short As[2][BM][BK];   // 16 KB
    __shared__ unsigned short Bs[2][BN][BK];   // 16 KB

    // XCD-aware swizzle (4096 blocks, 8 XCDs -> 512 contiguous per XCD),
    // m-fast: 32 consecutive blocks (same XCD) share one W n-panel in L2.
    const int bid = blockIdx.x;
    const int sw  = (bid & 7) * 512 + (bid >> 3);
    const int m0  = (sw & 31) * BM;
    const int n0  = (sw >> 5) * BN;

    const int t    = threadIdx.x;
    const int lane = t & 63;
    const int wave = t >> 6;
    const int wm   = (wave >> 1) * 64;   // wave M offset in tile
    const int wn   = (wave & 1) * 64;    // wave N offset in tile
    const int lr   = lane & 15;          // fragment row index
    const int lk   = (lane >> 4) * 8;    // fragment k offset (elems, covers BK=32)
    const int cf   = lk ^ ((lr & 3) << 3);  // swizzled frag k-col (row&3 == lr&3)

    // staging: thread owns LDS row nn (A-row m0+nn AND B-col n0+nn),
    // k-half [sh, sh+16) within the 32-wide K-step
    const int nn  = t & 127;
    const int sh  = (t >> 7) * 16;
    const int jm  = (n0 + nn) >> 6;          // masked k for this output col
    const int swz = (nn & 3) << 3;           // 2-bit XOR swizzle (row width 32)

    const float* Xp = X + (size_t)(m0 + nn) * K_DIM + sh;
    const float* Wp = W + (size_t)sh * N_DIM + (n0 + nn);

    float4 xa[4];     // A stage: 16 consecutive k of row m0+nn
    float  wv[16];    // B stage: 16 k of col n0+nn (stride-N dword, coalesced)

    auto issue = [&](int kt) {
        const float* xp = Xp + kt * BK;
        #pragma unroll
        for (int q = 0; q < 4; ++q) xa[q] = *(const float4*)(xp + q * 4);
        const float* wp = Wp + (size_t)(kt * BK) * N_DIM;
        #pragma unroll
        for (int j = 0; j < 16; ++j) wv[j] = wp[(size_t)j * N_DIM];
    };
    auto stage = [&](int kt, int buf) {
        const int kbase = kt * BK + sh;
        #pragma unroll
        for (int j = 0; j < 16; ++j)
            if (kbase + j == jm) wv[j] = 0.0f;    // bake the mask
        #pragma unroll
        for (int q = 0; q < 4; ++q) {
            const int c = (sh + q * 4) ^ swz;
            u32x2 bw = { pk2bf(wv[q * 4], wv[q * 4 + 1]),
                         pk2bf(wv[q * 4 + 2], wv[q * 4 + 3]) };
            *(u32x2*)&Bs[buf][nn][c] = bw;
            u32x2 aw = { pk2bf(xa[q].x, xa[q].y),
                         pk2bf(xa[q].z, xa[q].w) };
            *(u32x2*)&As[buf][nn][c] = aw;
        }
    };

    f32x4 acc[4][4] = {};

    issue(0);
    stage(0, 0);
    __syncthreads();

    #pragma unroll
    for (int kt = 0; kt < NKT; ++kt) {
        const int buf = kt & 1;
        if (kt + 1 < NKT) issue(kt + 1);   // loads in flight under MFMA

        short8 af[4], bfr[4];
        #pragma unroll
        for (int mi = 0; mi < 4; ++mi)
            af[mi] = *(const short8*)&As[buf][wm + mi * 16 + lr][cf];
        #pragma unroll
        for (int ni = 0; ni < 4; ++ni)
            bfr[ni] = *(const short8*)&Bs[buf][wn + ni * 16 + lr][cf];

        // Swapped operands: D[n][m] (verified R2): m = lane&15 (+mi*16),
        // n = (lane>>4)*4 + j (+ni*16)
        #pragma unroll
        for (int mi = 0; mi < 4; ++mi)
            #pragma unroll
            for (int ni = 0; ni < 4; ++ni)
                acc[mi][ni] = __builtin_amdgcn_mfma_f32_16x16x32_bf16(
                    bfr[ni], af[mi], acc[mi][ni], 0, 0, 0);

        if (kt + 1 < NKT) {
            stage(kt + 1, buf ^ 1);   // other buffer: no hazard with this kt's reads
            __syncthreads();
        }
    }

    // epilogue: direct f32x4 stores (R1 vs R3 showed segment size is minor;
    // no NT -> L2 write-combining assembles lines)
    const int om = m0 + wm + lr;
    const int on = n0 + wn + (lane >> 4) * 4;
    #pragma unroll
    for (int mi = 0; mi < 4; ++mi) {
        float* orow = out + (size_t)(om + mi * 16) * N_DIM;
        #pragma unroll
        for (int ni = 0; ni < 4; ++ni) {
            const int n = on + ni * 16;
            const float4 bv = *(const float4*)(bias + n);
            f32x4 v = acc[mi][ni];
            v[0] += bv.x; v[1] += bv.y; v[2] += bv.z; v[3] += bv.w;
            *(f32x4*)(orow + n) = v;
        }
    }
}

// ---------------------------------------------------------------------------
extern "C" void kernel_launch(void* const* d_in, const int* in_sizes, int n_in,
                              void* d_out, int out_size, void* d_ws, size_t ws_size,
                              hipStream_t stream) {
    const float* x    = (const float*)d_in[0];   // [4096, 256]
    const float* W    = (const float*)d_in[1];   // [256, 16384]
    const float* bias = (const float*)d_in[2];   // [16384]
    float* out        = (float*)d_out;           // [4096, 16384]

    fused_gemm_kernel<<<(M_DIM / BM) * (N_DIM / BN), 256, 0, stream>>>(x, W, bias, out);
}

// Round 6
// 104.602 us; speedup vs baseline: 1.6536x; 1.6536x over previous
//
#include <hip/hip_runtime.h>
#include <hip/hip_bf16.h>

#define M_DIM 4096
#define N_DIM 16384
#define K_DIM 256

typedef short short8 __attribute__((ext_vector_type(8)));
typedef float f32x4 __attribute__((ext_vector_type(4)));
typedef unsigned int u32x4 __attribute__((ext_vector_type(4)));

// fp32 -> bf16 (RNE) pack of two floats into one u32 (lo = first elem)
__device__ __forceinline__ unsigned int pk2bf(float lo, float hi) {
    unsigned int a = __float_as_uint(lo);
    unsigned int b = __float_as_uint(hi);
    a = (a + 0x7FFFu + ((a >> 16) & 1u)) >> 16;
    b = (b + 0x7FFFu + ((b >> 16) & 1u)) & 0xFFFF0000u;
    return a | b;
}

// ---------------------------------------------------------------------------
// Merged pre-pass (proven in R4):
//   blocks [0,128):   W [K][N] f32 -> Wt [N][K] bf16 (mask baked), via LDS
//                     transpose so BOTH global read and write are coalesced.
//   blocks [128,640): x [M][K] f32 -> xb bf16 flat.
// ---------------------------------------------------------------------------
__global__ __launch_bounds__(256) void convert_kernel(const float* __restrict__ W,
                                                      const float* __restrict__ x,
                                                      unsigned short* __restrict__ Wt,
                                                      unsigned short* __restrict__ xb) {
    __shared__ unsigned short tile[128][256];   // 64 KB, XOR-swizzled rows
    const int bx = blockIdx.x;
    const int t  = threadIdx.x;
    if (bx < 128) {
        const int n0 = bx * 128;
        const int nn = t & 127;                 // local n (row of Wt)
        const int kh = (t >> 7) * 128;          // k half this thread fills
        const int jm = (n0 + nn) >> 6;          // masked k for this n
        const int sw = (nn & 31) << 3;          // XOR swizzle (8-elem granule)
        for (int kk = 0; kk < 128; kk += 8) {
            float v[8];
            #pragma unroll
            for (int j = 0; j < 8; ++j) {
                const int k = kh + kk + j;
                const float f = W[(size_t)k * N_DIM + n0 + nn];   // coalesced
                v[j] = (k == jm) ? 0.0f : f;
            }
            u32x4 p = { pk2bf(v[0], v[1]), pk2bf(v[2], v[3]),
                        pk2bf(v[4], v[5]), pk2bf(v[6], v[7]) };
            *(u32x4*)&tile[nn][(kh + kk) ^ sw] = p;
        }
        __syncthreads();
        // write-out: per wave-instr 2 rows x 512 B contiguous
        const int kc = (t & 31) * 8;
        #pragma unroll
        for (int it = 0; it < 16; ++it) {
            const int n = it * 8 + (t >> 5);
            u32x4 p = *(const u32x4*)&tile[n][kc ^ ((n & 31) << 3)];
            *(u32x4*)(Wt + (size_t)(n0 + n) * K_DIM + kc) = p;
        }
    } else {
        const size_t base = ((size_t)(bx - 128) * 256 + t) * 8;
        float4 a = *(const float4*)(x + base);
        float4 b = *(const float4*)(x + base + 4);
        u32x4 p = { pk2bf(a.x, a.y), pk2bf(a.z, a.w),
                    pk2bf(b.x, b.y), pk2bf(b.z, b.w) };
        *(u32x4*)(xb + base) = p;
    }
}

// ---------------------------------------------------------------------------
// Main GEMM: out[M][N] = Abf[M][K] @ Wt[N][K]^T + bias, fp32 out.
// 128x128 tile, BK=64, SINGLE-buffered 32 KB LDS -> 3 blocks/CU (store-drain
// coverage; kernel is HBM-write-bound: 256 MB out, 41 us floor). Reg-staged
// prefetch of next K-tile under MFMA; 2 barriers/K-step. Conflict-free
// (row&7)<<3 XOR swizzle (BK=64 rows span all 32 banks; R5's BK=32 proved
// narrow rows conflict). n-fast block order within XCD: concurrent blocks
// write address-adjacent panels (linear drain like the 6.6 TB/s fills).
// Operands swapped (D[n][m], verified R2) -> f32x4 direct stores.
// ---------------------------------------------------------------------------
constexpr int BM = 128, BN = 128, BK = 64;

__global__ __launch_bounds__(256, 3) void gemm_kernel(
        const unsigned short* __restrict__ Abf,   // [M][K] bf16
        const unsigned short* __restrict__ Bbf,   // [N][K] bf16 (masked W^T)
        const float* __restrict__ bias,           // [N] f32
        float* __restrict__ out) {                // [M][N] f32
    __shared__ unsigned short As[BM][BK];         // 16 KB
    __shared__ unsigned short Bs[BN][BK];         // 16 KB

    // XCD-aware chunking, n-fast within XCD.
    const int bid = blockIdx.x;
    const int sw  = (bid & 7) * 512 + (bid >> 3);
    const int n0  = (sw & 127) * BN;
    const int m0  = (sw >> 7) * BM;

    const int t    = threadIdx.x;
    const int lane = t & 63;
    const int wave = t >> 6;
    const int wm   = (wave >> 1) * 64;   // wave M offset in tile
    const int wn   = (wave & 1) * 64;    // wave N offset in tile
    const int lr   = lane & 15;          // fragment row index
    const int lk   = (lane >> 4) * 8;    // fragment k offset (elems)

    // staging geometry: thread covers row srow(+32r), 8 elems at selk
    const int srow = t >> 3;             // 0..31
    const int selk = (t & 7) * 8;        // 0..56

    const unsigned short* gA = Abf + (size_t)(m0 + srow) * K_DIM + selk;
    const unsigned short* gB = Bbf + (size_t)(n0 + srow) * K_DIM + selk;

    u32x4 ra[4], rb[4];
    auto ldreg = [&](int kt) {
        #pragma unroll
        for (int r = 0; r < 4; ++r) {
            ra[r] = *(const u32x4*)(gA + (size_t)(r * 32) * K_DIM + kt * BK);
            rb[r] = *(const u32x4*)(gB + (size_t)(r * 32) * K_DIM + kt * BK);
        }
    };
    auto dswrite = [&]() {
        #pragma unroll
        for (int r = 0; r < 4; ++r) {
            const int row = srow + r * 32;
            const int c   = selk ^ ((row & 7) << 3);   // bank swizzle
            *(u32x4*)&As[row][c] = ra[r];
            *(u32x4*)&Bs[row][c] = rb[r];
        }
    };

    f32x4 acc[4][4] = {};

    ldreg(0);
    dswrite();
    __syncthreads();

    #pragma unroll
    for (int kt = 0; kt < 4; ++kt) {
        if (kt < 3) ldreg(kt + 1);    // next tile -> regs; hides under MFMA
        #pragma unroll
        for (int ks = 0; ks < 2; ++ks) {
            short8 af[4], bfr[4];
            #pragma unroll
            for (int mi = 0; mi < 4; ++mi) {
                const int row = wm + mi * 16 + lr;
                const int c   = (ks * 32 + lk) ^ ((row & 7) << 3);
                af[mi] = *(const short8*)&As[row][c];
            }
            #pragma unroll
            for (int ni = 0; ni < 4; ++ni) {
                const int row = wn + ni * 16 + lr;
                const int c   = (ks * 32 + lk) ^ ((row & 7) << 3);
                bfr[ni] = *(const short8*)&Bs[row][c];
            }
            // Swapped operands: D[n][m] (verified R2): m=lane&15(+mi*16),
            // n=(lane>>4)*4+j(+ni*16)
            #pragma unroll
            for (int mi = 0; mi < 4; ++mi)
                #pragma unroll
                for (int ni = 0; ni < 4; ++ni)
                    acc[mi][ni] = __builtin_amdgcn_mfma_f32_16x16x32_bf16(
                        bfr[ni], af[ks == 0 ? mi : mi], acc[mi][ni], 0, 0, 0);
        }
        if (kt < 3) {
            __syncthreads();          // all waves done reading this tile
            dswrite();                // overwrite single buffer
            __syncthreads();          // writes visible
        }
    }

    // epilogue: direct f32x4 stores (segment size proven minor R1 vs R3;
    // no NT -> L2 write-combining assembles full lines)
    const int om = m0 + wm + lr;
    const int on = n0 + wn + (lane >> 4) * 4;
    #pragma unroll
    for (int mi = 0; mi < 4; ++mi) {
        float* orow = out + (size_t)(om + mi * 16) * N_DIM;
        #pragma unroll
        for (int ni = 0; ni < 4; ++ni) {
            const int n = on + ni * 16;
            const float4 bv = *(const float4*)(bias + n);
            f32x4 v = acc[mi][ni];
            v[0] += bv.x; v[1] += bv.y; v[2] += bv.z; v[3] += bv.w;
            *(f32x4*)(orow + n) = v;
        }
    }
}

// ---------------------------------------------------------------------------
// Fallback (only if d_ws is too small): direct fp32, slow but correct.
// ---------------------------------------------------------------------------
__global__ __launch_bounds__(256) void fallback_kernel(const float* __restrict__ x,
                                                       const float* __restrict__ W,
                                                       const float* __restrict__ bias,
                                                       float* __restrict__ out) {
    const size_t gid = (size_t)blockIdx.x * 256 + threadIdx.x;
    const size_t row = gid / (N_DIM / 8);
    const int    c0  = (int)(gid % (N_DIM / 8)) * 8;
    const int    jm  = c0 >> 6;
    float acc[8] = {0, 0, 0, 0, 0, 0, 0, 0};
    const float* xr = x + row * K_DIM;
    for (int k = 0; k < K_DIM; ++k) {
        const float xv = (k == jm) ? 0.0f : xr[k];
        const float4* wr = (const float4*)(W + (size_t)k * N_DIM + c0);
        float4 w0 = wr[0], w1 = wr[1];
        acc[0] += xv * w0.x; acc[1] += xv * w0.y;
        acc[2] += xv * w0.z; acc[3] += xv * w0.w;
        acc[4] += xv * w1.x; acc[5] += xv * w1.y;
        acc[6] += xv * w1.z; acc[7] += xv * w1.w;
    }
    float* o = out + row * N_DIM + c0;
    #pragma unroll
    for (int j = 0; j < 8; ++j) o[j] = acc[j] + bias[c0 + j];
}

// ---------------------------------------------------------------------------
extern "C" void kernel_launch(void* const* d_in, const int* in_sizes, int n_in,
                              void* d_out, int out_size, void* d_ws, size_t ws_size,
                              hipStream_t stream) {
    const float* x    = (const float*)d_in[0];   // [4096, 256]
    const float* W    = (const float*)d_in[1];   // [256, 16384]
    const float* bias = (const float*)d_in[2];   // [16384]
    float* out        = (float*)d_out;           // [4096, 16384]

    const size_t wt_bytes = (size_t)N_DIM * K_DIM * 2;   // 8 MB
    const size_t xb_bytes = (size_t)M_DIM * K_DIM * 2;   // 2 MB

    if (ws_size >= wt_bytes + xb_bytes) {
        unsigned short* Wt = (unsigned short*)d_ws;
        unsigned short* xb = (unsigned short*)((char*)d_ws + wt_bytes);

        convert_kernel<<<128 + (M_DIM * K_DIM / 8) / 256, 256, 0, stream>>>(W, x, Wt, xb);
        gemm_kernel<<<(M_DIM / BM) * (N_DIM / BN), 256, 0, stream>>>(xb, Wt, bias, out);
    } else {
        const size_t total = (size_t)M_DIM * N_DIM / 8;
        fallback_kernel<<<(unsigned)(total / 256), 256, 0, stream>>>(x, W, bias, out);
    }
}

// Round 7
// 87.141 us; speedup vs baseline: 1.9849x; 1.2004x over previous
//
#include <hip/hip_runtime.h>
#include <hip/hip_bf16.h>

#define M_DIM 4096
#define N_DIM 16384
#define K_DIM 256

typedef short short8 __attribute__((ext_vector_type(8)));
typedef float f32x4 __attribute__((ext_vector_type(4)));
typedef unsigned int u32x4 __attribute__((ext_vector_type(4)));

// fp32 -> bf16 (RNE) pack of two floats into one u32 (lo = first elem)
__device__ __forceinline__ unsigned int pk2bf(float lo, float hi) {
    unsigned int a = __float_as_uint(lo);
    unsigned int b = __float_as_uint(hi);
    a = (a + 0x7FFFu + ((a >> 16) & 1u)) >> 16;
    b = (b + 0x7FFFu + ((b >> 16) & 1u)) & 0xFFFF0000u;
    return a | b;
}

// ---------------------------------------------------------------------------
// Pre-pass, one launch, 1024 blocks:
//   blocks [0,512):    W [K][N] f32 -> Wt [N][K] bf16 (mask baked) via LDS
//                      transpose. 4 k-chunks x 128 n-panels: 4x the
//                      parallelism of the R4 version. Reads: 256 B segments
//                      along n, 8 outstanding. Writes: 128 B full lines
//                      along k. ~24 MB traffic ≈ 4-5 us.
//   blocks [512,1024): x [M][K] f32 -> xb bf16 flat (float4 reads, 16B writes)
// ---------------------------------------------------------------------------
__global__ __launch_bounds__(256) void convert_kernel(const float* __restrict__ W,
                                                      const float* __restrict__ x,
                                                      unsigned short* __restrict__ Wt,
                                                      unsigned short* __restrict__ xb) {
    const int bx = blockIdx.x;
    const int t  = threadIdx.x;
    if (bx < 512) {
        __shared__ unsigned short tile[128][64];   // 16 KB, XOR-swizzled rows
        const int n0  = (bx & 127) * 128;          // n-panel
        const int kc0 = (bx >> 7) * 64;            // k-chunk
        const int nn  = t & 127;                   // local n (row of tile)
        const int kh  = (t >> 7) * 32;             // k-half this thread fills
        const int jm  = (n0 + nn) >> 6;            // masked k for this n
        const int sw  = (nn & 7) << 3;             // XOR swizzle (8-elem granule)
        #pragma unroll
        for (int kk = 0; kk < 32; kk += 8) {
            float v[8];
            #pragma unroll
            for (int j = 0; j < 8; ++j) {
                const int k = kc0 + kh + kk + j;
                const float f = W[(size_t)k * N_DIM + n0 + nn];   // coalesced in n
                v[j] = (k == jm) ? 0.0f : f;
            }
            u32x4 p = { pk2bf(v[0], v[1]), pk2bf(v[2], v[3]),
                        pk2bf(v[4], v[5]), pk2bf(v[6], v[7]) };
            *(u32x4*)&tile[nn][(kh + kk) ^ sw] = p;
        }
        __syncthreads();
        // write-out: per wave-instr 8 n-rows x 128 B aligned full lines
        const int kc = (t & 7) * 8;
        const int nr = t >> 3;
        #pragma unroll
        for (int it = 0; it < 4; ++it) {
            const int n = it * 32 + nr;
            u32x4 p = *(const u32x4*)&tile[n][kc ^ ((n & 7) << 3)];
            *(u32x4*)(Wt + (size_t)(n0 + n) * K_DIM + kc0 + kc) = p;
        }
    } else {
        const size_t base = ((size_t)(bx - 512) * 256 + t) * 8;
        float4 a = *(const float4*)(x + base);
        float4 b = *(const float4*)(x + base + 4);
        u32x4 p = { pk2bf(a.x, a.y), pk2bf(a.z, a.w),
                    pk2bf(b.x, b.y), pk2bf(b.z, b.w) };
        *(u32x4*)(xb + base) = p;
    }
}

// ---------------------------------------------------------------------------
// Main GEMM — VERBATIM the round-3 structure (best measured: 88.2 total).
// out[M][N] = Abf[M][K] @ Wt[N][K]^T + bias, fp32 out.
// 128x128 tile, BK=64, 4 waves (2x2), 4x4 frags of mfma_f32_16x16x32_bf16,
// operands swapped (D[n][m], verified R2). Double-buffered 64 KB LDS,
// reg-staged prefetch, m-fast XCD ordering, Cs-staged coalesced epilogue.
// ---------------------------------------------------------------------------
constexpr int BM = 128, BN = 128, BK = 64;

__global__ __launch_bounds__(256, 2) void gemm_kernel(
        const unsigned short* __restrict__ Abf,   // [M][K] bf16
        const unsigned short* __restrict__ Bbf,   // [N][K] bf16 (masked W^T)
        const float* __restrict__ bias,           // [N] f32
        float* __restrict__ out) {                // [M][N] f32
    __shared__ __align__(16) unsigned char smem[65536];
    auto As = (unsigned short (*)[BM][BK])(smem);
    auto Bs = (unsigned short (*)[BN][BK])(smem + 32768);
    float* Cs = (float*)smem;

    const int bid = blockIdx.x;
    const int sw  = (bid & 7) * 512 + (bid >> 3);
    const int m0  = (sw & 31) * BM;
    const int n0  = (sw >> 5) * BN;

    const int t    = threadIdx.x;
    const int lane = t & 63;
    const int wave = t >> 6;
    const int wm   = (wave >> 1) * 64;
    const int wn   = (wave & 1) * 64;
    const int lr   = lane & 15;
    const int lk   = (lane >> 4) * 8;

    const int srow = t >> 3;
    const int selk = (t & 7) * 8;

    const unsigned short* gA = Abf + (size_t)(m0 + srow) * K_DIM + selk;
    const unsigned short* gB = Bbf + (size_t)(n0 + srow) * K_DIM + selk;

    u32x4 ra[4], rb[4];

    auto ldreg = [&](int kt) {
        #pragma unroll
        for (int r = 0; r < 4; ++r) {
            ra[r] = *(const u32x4*)(gA + (size_t)(r * 32) * K_DIM + kt * BK);
            rb[r] = *(const u32x4*)(gB + (size_t)(r * 32) * K_DIM + kt * BK);
        }
    };
    auto dswrite = [&](int buf) {
        #pragma unroll
        for (int r = 0; r < 4; ++r) {
            const int row = srow + r * 32;
            const int c   = selk ^ ((row & 7) << 3);
            *(u32x4*)&As[buf][row][c] = ra[r];
            *(u32x4*)&Bs[buf][row][c] = rb[r];
        }
    };

    f32x4 acc[4][4] = {};

    ldreg(0);
    dswrite(0);
    __syncthreads();

    #pragma unroll
    for (int kt = 0; kt < 4; ++kt) {
        const int buf = kt & 1;
        if (kt < 3) ldreg(kt + 1);
        #pragma unroll
        for (int ks = 0; ks < 2; ++ks) {
            short8 af[4], bfr[4];
            #pragma unroll
            for (int mi = 0; mi < 4; ++mi) {
                const int row = wm + mi * 16 + lr;
                const int c   = (ks * 32 + lk) ^ ((row & 7) << 3);
                af[mi] = *(const short8*)&As[buf][row][c];
            }
            #pragma unroll
            for (int ni = 0; ni < 4; ++ni) {
                const int row = wn + ni * 16 + lr;
                const int c   = (ks * 32 + lk) ^ ((row & 7) << 3);
                bfr[ni] = *(const short8*)&Bs[buf][row][c];
            }
            // Swapped operands: D[n][m] (verified R2): m=lane&15(+mi*16),
            // n=(lane>>4)*4+j(+ni*16)
            #pragma unroll
            for (int mi = 0; mi < 4; ++mi)
                #pragma unroll
                for (int ni = 0; ni < 4; ++ni)
                    acc[mi][ni] = __builtin_amdgcn_mfma_f32_16x16x32_bf16(
                        bfr[ni], af[mi], acc[mi][ni], 0, 0, 0);
        }
        if (kt < 3) {
            dswrite(buf ^ 1);
            __syncthreads();
        }
    }

    // ---- epilogue: acc -> LDS (swizzled) -> coalesced global stores ----
    __syncthreads();   // all waves done reading As/Bs before aliasing as Cs

    {
        const int rl0 = wm + lr;                  // local row for this lane
        const int nl0 = wn + (lane >> 4) * 4;     // local col (float index)
        #pragma unroll
        for (int mi = 0; mi < 4; ++mi) {
            const int rl = rl0 + mi * 16;
            const int sx = (rl & 7) << 2;         // XOR swizzle, 4-float granule
            #pragma unroll
            for (int ni = 0; ni < 4; ++ni) {
                const int nl = (nl0 + ni * 16) ^ sx;
                *(f32x4*)&Cs[rl * BN + nl] = acc[mi][ni];
            }
        }
    }
    __syncthreads();

    {
        const int col4 = (t & 31) * 4;            // float col, 0..124
        const float4 bv = *(const float4*)(bias + n0 + col4);
        #pragma unroll
        for (int p = 0; p < 16; ++p) {
            const int row = p * 8 + (t >> 5);
            const int cs  = col4 ^ ((row & 7) << 2);
            f32x4 v = *(const f32x4*)&Cs[row * BN + cs];
            v[0] += bv.x; v[1] += bv.y; v[2] += bv.z; v[3] += bv.w;
            *(f32x4*)(out + (size_t)(m0 + row) * N_DIM + n0 + col4) = v;
        }
    }
}

// ---------------------------------------------------------------------------
// Fallback (only if d_ws is too small): direct fp32, slow but correct.
// ---------------------------------------------------------------------------
__global__ __launch_bounds__(256) void fallback_kernel(const float* __restrict__ x,
                                                       const float* __restrict__ W,
                                                       const float* __restrict__ bias,
                                                       float* __restrict__ out) {
    const size_t gid = (size_t)blockIdx.x * 256 + threadIdx.x;
    const size_t row = gid / (N_DIM / 8);
    const int    c0  = (int)(gid % (N_DIM / 8)) * 8;
    const int    jm  = c0 >> 6;
    float acc[8] = {0, 0, 0, 0, 0, 0, 0, 0};
    const float* xr = x + row * K_DIM;
    for (int k = 0; k < K_DIM; ++k) {
        const float xv = (k == jm) ? 0.0f : xr[k];
        const float4* wr = (const float4*)(W + (size_t)k * N_DIM + c0);
        float4 w0 = wr[0], w1 = wr[1];
        acc[0] += xv * w0.x; acc[1] += xv * w0.y;
        acc[2] += xv * w0.z; acc[3] += xv * w0.w;
        acc[4] += xv * w1.x; acc[5] += xv * w1.y;
        acc[6] += xv * w1.z; acc[7] += xv * w1.w;
    }
    float* o = out + row * N_DIM + c0;
    #pragma unroll
    for (int j = 0; j < 8; ++j) o[j] = acc[j] + bias[c0 + j];
}

// ---------------------------------------------------------------------------
extern "C" void kernel_launch(void* const* d_in, const int* in_sizes, int n_in,
                              void* d_out, int out_size, void* d_ws, size_t ws_size,
                              hipStream_t stream) {
    const float* x    = (const float*)d_in[0];   // [4096, 256]
    const float* W    = (const float*)d_in[1];   // [256, 16384]
    const float* bias = (const float*)d_in[2];   // [16384]
    float* out        = (float*)d_out;           // [4096, 16384]

    const size_t wt_bytes = (size_t)N_DIM * K_DIM * 2;   // 8 MB
    const size_t xb_bytes = (size_t)M_DIM * K_DIM * 2;   // 2 MB

    if (ws_size >= wt_bytes + xb_bytes) {
        unsigned short* Wt = (unsigned short*)d_ws;
        unsigned short* xb = (unsigned short*)((char*)d_ws + wt_bytes);

        convert_kernel<<<512 + (M_DIM * K_DIM / 8) / 256, 256, 0, stream>>>(W, x, Wt, xb);
        gemm_kernel<<<(M_DIM / BM) * (N_DIM / BN), 256, 0, stream>>>(xb, Wt, bias, out);
    } else {
        const size_t total = (size_t)M_DIM * N_DIM / 8;
        fallback_kernel<<<(unsigned)(total / 256), 256, 0, stream>>>(x, W, bias, out);
    }
}